// Round 10
// baseline (430.328 us; speedup 1.0000x reference)
//
#include <hip/hip_runtime.h>
#include <cstdint>

#define D_MODEL 768
#define NHEAD 12
#define DK 64
#define BATCH 2
#define SEQ 4096
#define MTOT (BATCH * SEQ)  // 8192
#define NT (SEQ / 64)       // 64 K-tiles
#define WSZ (D_MODEL * D_MODEL)

typedef __attribute__((ext_vector_type(8))) _Float16 f16x8;  // 4 VGPRs
typedef __attribute__((ext_vector_type(4))) float f32x4;
typedef unsigned short ushort_t;
typedef unsigned int uint_t;

#define SCALE_LOG2E 0.18033688011112042f  // 0.125 * log2(e)
#define EXP2(d, s) asm("v_exp_f32 %0, %1" : "=v"(d) : "v"(s))

// XOR-swizzled byte offset in a row-major tile with 128B rows (64 f16/row)
__device__ __forceinline__ int swz(int row, int col_e) {
    return (row * 128 + col_e * 2) ^ ((row & 7) << 4);
}

__device__ __forceinline__ uint_t pkrtz(float a, float b) {
    return __builtin_bit_cast(uint_t, __builtin_amdgcn_cvt_pkrtz(a, b));
}

// global -> LDS direct copy, 16B/lane, linear dest; source pre-swizzled (rule #21)
__device__ __forceinline__ void gl_lds16(const ushort_t* g, char* l) {
    __builtin_amdgcn_global_load_lds((const __attribute__((address_space(1))) void*)g,
                                     (__attribute__((address_space(3))) void*)l, 16, 0, 0);
}

// ============ fp32 -> fp16 (RNE) bulk convert: 7 tensors in one launch ============
__global__ __launch_bounds__(256) void cvt7(const float* s0, const float* s1, const float* s2,
                                            const float* s3, const float* s4, const float* s5,
                                            const float* s6, ushort_t* d0, ushort_t* d1,
                                            ushort_t* d2, ushort_t* d3, ushort_t* d4,
                                            ushort_t* d5, ushort_t* d6) {
    const int t = blockIdx.y;
    const float* src;
    ushort_t* dst;
    int n;
    if (t == 0) { src = s0; dst = d0; n = MTOT * D_MODEL; }
    else if (t == 1) { src = s1; dst = d1; n = MTOT * D_MODEL; }
    else if (t == 2) { src = s2; dst = d2; n = MTOT * D_MODEL; }
    else if (t == 3) { src = s3; dst = d3; n = WSZ; }
    else if (t == 4) { src = s4; dst = d4; n = WSZ; }
    else if (t == 5) { src = s5; dst = d5; n = WSZ; }
    else { src = s6; dst = d6; n = WSZ; }
    const int i = (blockIdx.x * 256 + threadIdx.x) * 8;
    if (i >= n) return;
    float4 a = *(const float4*)(src + i);
    float4 b = *(const float4*)(src + i + 4);
    f16x8 h;  // RNE casts
    h[0] = (_Float16)a.x; h[1] = (_Float16)a.y; h[2] = (_Float16)a.z; h[3] = (_Float16)a.w;
    h[4] = (_Float16)b.x; h[5] = (_Float16)b.y; h[6] = (_Float16)b.z; h[7] = (_Float16)b.w;
    *(f16x8*)(dst + i) = h;
}

// ============ staging for gemm (unchanged from R9, passing) ============
__device__ __forceinline__ void stage_gemm(const ushort_t* __restrict__ Ap,
                                           const ushort_t* __restrict__ Wp,
                                           int m0, int n0, int k0, char* ldsbuf,
                                           int w, int lane) {
    const int r8 = lane >> 3;
    const int cole = (((lane & 7) * 16) ^ (r8 << 4)) >> 1;  // pre-swz col in elems
#pragma unroll
    for (int j = 0; j < 4; ++j)
        gl_lds16(Ap + (size_t)(m0 + w * 32 + j * 8 + r8) * D_MODEL + k0 + cole,
                 ldsbuf + w * 4096 + j * 1024);
#pragma unroll
    for (int j = 0; j < 2; ++j)
        gl_lds16(Wp + (size_t)(n0 + w * 16 + j * 8 + r8) * D_MODEL + k0 + cole,
                 ldsbuf + 16384 + w * 2048 + j * 1024);
}

// ============ fp16 MFMA GEMM (R9 body + XCD-aware block swizzle, T1) ============
// BM=128, BN=64, BK=64; 256 thr = 4 waves (2x2); LDS dbuf; one barrier/iter.
// Block swizzle: lin = bx + 12*by (0..767); sw = (lin&7)*96 + lin>>3 (bijective,
// 768 = 8*96) -> each XCD gets 8 contiguous m-bands: A-band + W stay L2-resident.
// MODE 1: C fp16 head layout [B,H,S,DK], scaled by alpha ; MODE 0: C fp32 [M][768]
template <int MODE>
__global__ __launch_bounds__(256) void gemm_f16(const ushort_t* __restrict__ Ap,
                                                const ushort_t* __restrict__ Wp,
                                                const float* __restrict__ bias,
                                                void* __restrict__ Cp,
                                                float alpha) {
    __shared__ __align__(16) char lds[49152];
    const int tid = threadIdx.x;
    const int lane = tid & 63;
    const int w = tid >> 6;
    const int li = lane & 15;
    const int g = lane >> 4;
    const int wr = w >> 1, wc = w & 1;
    const int lin = blockIdx.x + 12 * blockIdx.y;
    const int sw = (lin & 7) * 96 + (lin >> 3);
    const int nx = sw % 12;
    const int m0 = (sw / 12) * 128;
    const int n0 = nx * 64;

    f32x4 acc[4][2];
#pragma unroll
    for (int fr = 0; fr < 4; ++fr)
#pragma unroll
        for (int fc = 0; fc < 2; ++fc) acc[fr][fc] = (f32x4){0.f, 0.f, 0.f, 0.f};

    stage_gemm(Ap, Wp, m0, n0, 0, lds, w, lane);
    __syncthreads();  // buf0 ready

    for (int kk = 0; kk < 6; ++kk) {
#pragma unroll
        for (int ph = 0; ph < 2; ++ph) {
            const int it = kk * 2 + ph;  // 0..11
            char* cur = lds + (ph ? 24576 : 0);
            if (it + 1 < 12)
                stage_gemm(Ap, Wp, m0, n0, (it + 1) * 64, lds + (ph ? 0 : 24576), w, lane);
#pragma unroll
            for (int ks = 0; ks < 2; ++ks) {
                f16x8 ar[4], br[2];
#pragma unroll
                for (int fr = 0; fr < 4; ++fr)
                    ar[fr] = *(const f16x8*)(cur + swz(wr * 64 + fr * 16 + li, ks * 32 + g * 8));
#pragma unroll
                for (int fc = 0; fc < 2; ++fc)
                    br[fc] = *(const f16x8*)(cur + 16384 + swz(wc * 32 + fc * 16 + li, ks * 32 + g * 8));
#pragma unroll
                for (int fr = 0; fr < 4; ++fr)
#pragma unroll
                    for (int fc = 0; fc < 2; ++fc)
                        acc[fr][fc] = __builtin_amdgcn_mfma_f32_16x16x32_f16(ar[fr], br[fc], acc[fr][fc], 0, 0, 0);
            }
            if (it + 1 < 12) __syncthreads();
        }
    }

#pragma unroll
    for (int fr = 0; fr < 4; ++fr)
#pragma unroll
        for (int fc = 0; fc < 2; ++fc)
#pragma unroll
            for (int r = 0; r < 4; ++r) {
                const int m = m0 + wr * 64 + fr * 16 + g * 4 + r;
                const int d = wc * 32 + fc * 16 + li;
                float val = acc[fr][fc][r] + bias[n0 + d];
                if (MODE == 0) {
                    ((float*)Cp)[(size_t)m * D_MODEL + n0 + d] = val;
                } else {
                    val *= alpha;
                    const int b = m >> 12;
                    const int s = m & (SEQ - 1);
                    const size_t idx = (((size_t)b * NHEAD + nx) * SEQ + s) * DK + d;
                    ((ushort_t*)Cp)[idx] = __builtin_bit_cast(ushort_t, (_Float16)val);
                }
            }
}

// ============ fp16 MFMA flash attention v6: 2 q-sets per wave ============
// 256 thr = 4 waves; wave w owns q-rows [q0 + w*32, +32) as 2 sets of 16.
// kf read once feeds both sets' QK^T; vf read once (transient) feeds both PV.
// K via gload_lds (pre-swz source), V transposed via scalar gather (proven).
// K/V LDS dbuf, ONE barrier/tile. P region (2KB/wave) reused per set
// (same-wave in-order LDS). Output fp16 row-major [MTOT][768].
__global__ __launch_bounds__(256, 4) void flash6(const ushort_t* __restrict__ q_g,
                                                 const ushort_t* __restrict__ k_g,
                                                 const ushort_t* __restrict__ v_g,
                                                 ushort_t* __restrict__ aw) {
    __shared__ __align__(16) char lds[40960];
    // Kbuf: 0 / 8192 ; Vtbuf: 16384 / 24576 ; P: 32768 + w*2048

    const int tid = threadIdx.x;  // 0..255
    const int lane = tid & 63;
    const int w = tid >> 6;       // 0..3
    const int li = lane & 15;
    const int g = lane >> 4;
    const int bh = blockIdx.y;
    const int q0 = blockIdx.x * 128;

    const ushort_t* qp = q_g + (size_t)bh * SEQ * DK;
    const ushort_t* kp = k_g + (size_t)bh * SEQ * DK;
    const ushort_t* vp = v_g + (size_t)bh * SEQ * DK;

    // Q fragments (2 sets) straight from global
    f16x8 qf[2][2];
#pragma unroll
    for (int h = 0; h < 2; ++h)
#pragma unroll
        for (int ks = 0; ks < 2; ++ks)
            qf[h][ks] = *(const f16x8*)(qp + (size_t)(q0 + w * 32 + h * 16 + li) * DK + ks * 32 + g * 8);

    // K gload geometry: wave w covers tile rows [w*16, +16) in 2 chunks of 8
    const int kr8 = lane >> 3;
    const int kcole = (((lane & 7) * 16) ^ (kr8 << 4)) >> 1;
    const ushort_t* ksrc = kp + (size_t)(w * 16 + kr8) * DK + kcole;
    // V gather: lane = d column; wave w covers k rows [w*16, +16)
    const int vd = lane;
    const ushort_t* vsrc = vp + (size_t)(w * 16) * DK + vd;
    const int vw0 = swz(vd, w * 16);
    const int vw1 = swz(vd, w * 16 + 4);
    const int vw2 = swz(vd, w * 16 + 8);
    const int vw3 = swz(vd, w * 16 + 12);

    // ---- prologue: stage tile 0 into buffers 0
    gl_lds16(ksrc, lds + 0 + w * 2048);
    gl_lds16(ksrc + 8 * DK, lds + 0 + w * 2048 + 1024);
    ushort_t vr[16];
#pragma unroll
    for (int j = 0; j < 16; ++j) vr[j] = vsrc[(size_t)j * DK];
    {
        ushort4 u;
        u.x = vr[0]; u.y = vr[1]; u.z = vr[2]; u.w = vr[3];
        *(ushort4*)(lds + 16384 + vw0) = u;
        u.x = vr[4]; u.y = vr[5]; u.z = vr[6]; u.w = vr[7];
        *(ushort4*)(lds + 16384 + vw1) = u;
        u.x = vr[8]; u.y = vr[9]; u.z = vr[10]; u.w = vr[11];
        *(ushort4*)(lds + 16384 + vw2) = u;
        u.x = vr[12]; u.y = vr[13]; u.z = vr[14]; u.w = vr[15];
        *(ushort4*)(lds + 16384 + vw3) = u;
    }
    __syncthreads();  // buffers 0 ready

    f32x4 oacc[2][4];
#pragma unroll
    for (int h = 0; h < 2; ++h)
#pragma unroll
        for (int i = 0; i < 4; ++i) oacc[h][i] = (f32x4){0.f, 0.f, 0.f, 0.f};
    float m_r[2] = {-1e30f, -1e30f}, l_r[2] = {0.f, 0.f};

    const int pb = 32768 + w * 2048;

    for (int kt2 = 0; kt2 < NT / 2; ++kt2) {
#pragma unroll
        for (int ph = 0; ph < 2; ++ph) {  // static indices
            const int kt = kt2 * 2 + ph;
            const int KBc = ph ? 8192 : 0;
            const int KBn = ph ? 0 : 8192;
            const int VBc = ph ? 24576 : 16384;
            const int VBn = ph ? 16384 : 24576;
            const bool pre = (kt + 1 < NT);

            // T14: issue next tile's K gload + V gathers now
            if (pre) {
                gl_lds16(ksrc + (size_t)(kt + 1) * 64 * DK, lds + KBn + w * 2048);
                gl_lds16(ksrc + (size_t)((kt + 1) * 64 + 8) * DK, lds + KBn + w * 2048 + 1024);
#pragma unroll
                for (int j = 0; j < 16; ++j)
                    vr[j] = vsrc[((size_t)(kt + 1) * 64 + j) * DK];
            }

            // ---- S^T = mfma(K, Q) for both q-sets; kf read once
            f32x4 sacc[2][4];
#pragma unroll
            for (int h = 0; h < 2; ++h)
#pragma unroll
                for (int t = 0; t < 4; ++t) sacc[h][t] = (f32x4){0.f, 0.f, 0.f, 0.f};
            __builtin_amdgcn_s_setprio(1);
#pragma unroll
            for (int t = 0; t < 4; ++t)
#pragma unroll
                for (int ks = 0; ks < 2; ++ks) {
                    f16x8 kf = *(const f16x8*)(lds + KBc + swz(t * 16 + li, ks * 32 + g * 8));
                    sacc[0][t] = __builtin_amdgcn_mfma_f32_16x16x32_f16(kf, qf[0][ks], sacc[0][t], 0, 0, 0);
                    sacc[1][t] = __builtin_amdgcn_mfma_f32_16x16x32_f16(kf, qf[1][ks], sacc[1][t], 0, 0, 0);
                }
            __builtin_amdgcn_s_setprio(0);

            // ---- softmax (log2 domain), defer-max over both sets
            float mx[2];
#pragma unroll
            for (int h = 0; h < 2; ++h) {
                float t0 = fmaxf(fmaxf(sacc[h][0][0], sacc[h][0][1]), fmaxf(sacc[h][0][2], sacc[h][0][3]));
                float t1 = fmaxf(fmaxf(sacc[h][1][0], sacc[h][1][1]), fmaxf(sacc[h][1][2], sacc[h][1][3]));
                float t2 = fmaxf(fmaxf(sacc[h][2][0], sacc[h][2][1]), fmaxf(sacc[h][2][2], sacc[h][2][3]));
                float t3 = fmaxf(fmaxf(sacc[h][3][0], sacc[h][3][1]), fmaxf(sacc[h][3][2], sacc[h][3][3]));
                float m = fmaxf(fmaxf(t0, t1), fmaxf(t2, t3));
                m = fmaxf(m, __shfl_xor(m, 16));
                m = fmaxf(m, __shfl_xor(m, 32));
                mx[h] = m;
            }
            if (__any((mx[0] > m_r[0] + 8.0f) || (mx[1] > m_r[1] + 8.0f))) {
#pragma unroll
                for (int h = 0; h < 2; ++h) {
                    const float nm = fmaxf(m_r[h], mx[h]);
                    float corr;
                    float dd = m_r[h] - nm;
                    EXP2(corr, dd);
                    m_r[h] = nm;
                    l_r[h] *= corr;
#pragma unroll
                    for (int dt = 0; dt < 4; ++dt) oacc[h][dt] *= corr;
                }
            }

            // ---- P per set: exp2, pack, write to wave-private P, read back frag
            // (set1 overwrites set0's region AFTER set0's pbf reads: same-wave
            //  in-order LDS => safe, no barrier)
            f16x8 pbf[2][2];
#pragma unroll
            for (int h = 0; h < 2; ++h) {
#pragma unroll
                for (int t = 0; t < 4; ++t) {
                    float p0, p1, p2, p3;
                    float e0 = sacc[h][t][0] - m_r[h];
                    float e1 = sacc[h][t][1] - m_r[h];
                    float e2 = sacc[h][t][2] - m_r[h];
                    float e3 = sacc[h][t][3] - m_r[h];
                    EXP2(p0, e0); EXP2(p1, e1); EXP2(p2, e2); EXP2(p3, e3);
                    l_r[h] += (p0 + p1) + (p2 + p3);
                    uint2 pk;
                    pk.x = pkrtz(p0, p1);
                    pk.y = pkrtz(p2, p3);
                    *(uint2*)(lds + pb + swz(li, t * 16 + g * 4)) = pk;
                }
#pragma unroll
                for (int ks = 0; ks < 2; ++ks)
                    pbf[h][ks] = *(const f16x8*)(lds + pb + swz(li, ks * 32 + g * 8));
            }

            // ---- O^T += mfma(Vt, P) for both sets; vf read once (transient)
            __builtin_amdgcn_s_setprio(1);
#pragma unroll
            for (int dt = 0; dt < 4; ++dt)
#pragma unroll
                for (int ks = 0; ks < 2; ++ks) {
                    f16x8 vf = *(const f16x8*)(lds + VBc + swz(dt * 16 + li, ks * 32 + g * 8));
                    oacc[0][dt] = __builtin_amdgcn_mfma_f32_16x16x32_f16(vf, pbf[0][ks], oacc[0][dt], 0, 0, 0);
                    oacc[1][dt] = __builtin_amdgcn_mfma_f32_16x16x32_f16(vf, pbf[1][ks], oacc[1][dt], 0, 0, 0);
                }
            __builtin_amdgcn_s_setprio(0);

            // ---- publish next V tile, then the ONE barrier
            if (pre) {
                ushort4 u;
                u.x = vr[0]; u.y = vr[1]; u.z = vr[2]; u.w = vr[3];
                *(ushort4*)(lds + VBn + vw0) = u;
                u.x = vr[4]; u.y = vr[5]; u.z = vr[6]; u.w = vr[7];
                *(ushort4*)(lds + VBn + vw1) = u;
                u.x = vr[8]; u.y = vr[9]; u.z = vr[10]; u.w = vr[11];
                *(ushort4*)(lds + VBn + vw2) = u;
                u.x = vr[12]; u.y = vr[13]; u.z = vr[14]; u.w = vr[15];
                *(ushort4*)(lds + VBn + vw3) = u;
                __syncthreads();  // drains next-K gload + publishes next-V
            }
        }
    }

    // ---- epilogue
    const int b = bh / NHEAD;
    const int hh = bh % NHEAD;
#pragma unroll
    for (int h = 0; h < 2; ++h) {
        float lt = l_r[h];
        lt += __shfl_xor(lt, 16);
        lt += __shfl_xor(lt, 32);
        const float inv = 1.0f / lt;
        const int qrow = q0 + w * 32 + h * 16 + li;
#pragma unroll
        for (int dt = 0; dt < 4; ++dt) {
            uint2 o;
            o.x = pkrtz(oacc[h][dt][0] * inv, oacc[h][dt][1] * inv);
            o.y = pkrtz(oacc[h][dt][2] * inv, oacc[h][dt][3] * inv);
            *(uint2*)&aw[((size_t)b * SEQ + qrow) * D_MODEL + hh * DK + dt * 16 + g * 4] = o;
        }
    }
}

extern "C" void kernel_launch(void* const* d_in, const int* in_sizes, int n_in,
                              void* d_out, int out_size, void* d_ws, size_t ws_size,
                              hipStream_t stream) {
    const float* q_in = (const float*)d_in[0];
    const float* k_in = (const float*)d_in[1];
    const float* v_in = (const float*)d_in[2];
    const float* Wq = (const float*)d_in[3];
    const float* bq = (const float*)d_in[4];
    const float* Wk = (const float*)d_in[5];
    const float* bk = (const float*)d_in[6];
    const float* Wv = (const float*)d_in[7];
    const float* bv = (const float*)d_in[8];
    const float* Wo = (const float*)d_in[9];
    const float* bo = (const float*)d_in[10];
    float* out = (float*)d_out;

    const size_t per = (size_t)MTOT * D_MODEL;  // 6,291,456 elems
    ushort_t* x16q = (ushort_t*)d_ws;
    ushort_t* x16k = x16q + per;
    ushort_t* x16v = x16k + per;
    ushort_t* w16 = x16v + per;  // 4 x WSZ (Wq, Wk, Wv, Wo)
    ushort_t* qh = w16 + 4 * (size_t)WSZ;
    ushort_t* kh = qh + per;
    ushort_t* vh = kh + per;
    ushort_t* aw = vh + per;  // total ~93 MB

    dim3 blk(256);
    dim3 gcvt(MTOT * D_MODEL / (256 * 8), 7);  // (3072, 7)
    hipLaunchKernelGGL(cvt7, gcvt, blk, 0, stream, q_in, k_in, v_in, Wq, Wk, Wv, Wo,
                       x16q, x16k, x16v, w16, w16 + WSZ, w16 + 2 * WSZ, w16 + 3 * WSZ);

    dim3 gproj(D_MODEL / 64, MTOT / 128);  // (12, 64)
    hipLaunchKernelGGL((gemm_f16<1>), gproj, blk, 0, stream, x16q, w16, bq, qh, SCALE_LOG2E);
    hipLaunchKernelGGL((gemm_f16<1>), gproj, blk, 0, stream, x16k, w16 + WSZ, bk, kh, 1.0f);
    hipLaunchKernelGGL((gemm_f16<1>), gproj, blk, 0, stream, x16v, w16 + 2 * WSZ, bv, vh, 1.0f);

    dim3 gattn(SEQ / 128, BATCH * NHEAD);  // (32, 24)
    hipLaunchKernelGGL(flash6, gattn, blk, 0, stream, qh, kh, vh, aw);

    hipLaunchKernelGGL((gemm_f16<0>), gproj, blk, 0, stream, aw, w16 + 3 * WSZ, bo, out, 1.0f);
}